// Round 5
// baseline (244.839 us; speedup 1.0000x reference)
//
#include <hip/hip_runtime.h>

// GraphSAGE 2-layer inference. N=40000, E=640000, C=128, OUT=121.
// R5: (a) CSR build with ONE atomic pass: k_rank stores atomicAdd-returned
// per-dst rank; k_place scatters with no atomics (pos = off+bpre+rank).
// (b) aggregate fused into the MFMA GEMM: block aggregates 128 nodes into an
// LDS A-tile (bf16, +8 short pad), then dual-GEMM reads agg frags from LDS,
// self frags from global. 7 dispatches total.

#define NCH 128

typedef __bf16 bf16x8 __attribute__((ext_vector_type(8)));
typedef float f32x4 __attribute__((ext_vector_type(4)));
typedef unsigned short ushort8 __attribute__((ext_vector_type(8)));

static __device__ __forceinline__ unsigned short f2b(float f) {
  return __builtin_bit_cast(unsigned short, static_cast<__bf16>(f));
}
static __device__ __forceinline__ float b2f(unsigned short u) {
  union { unsigned int i; float f; } v;
  v.i = ((unsigned int)u) << 16;
  return v.f;
}

// ---------------- fused setup: zero counters, x->bf16, weight prepack ----------------
// pack[c][t][lane][j] = W'[c*32 + (lane>>4)*8 + j][t*16 + (lane&15)]
// (B-frag for mfma_f32_16x16x32_bf16: n=lane&15, k=(lane>>4)*8+j); W' = [Wl;Wr].
__global__ __launch_bounds__(256) void k_setup(
    const float* __restrict__ x, unsigned short* __restrict__ xb, int n4,
    int* __restrict__ cnt, int N,
    const float* __restrict__ W1l, const float* __restrict__ W1r,
    const float* __restrict__ b1l, const float* __restrict__ b1r,
    const float* __restrict__ W2l, const float* __restrict__ W2r,
    const float* __restrict__ b2l, const float* __restrict__ b2r,
    unsigned short* __restrict__ pack1, unsigned short* __restrict__ pack2,
    float* __restrict__ bsum1, float* __restrict__ bsum2, int NOUT,
    int nbCvt, int nbZero) {
  int blk = blockIdx.x;
  if (blk < nbCvt) {  // fp32 -> bf16 convert
    int i = blk * 256 + threadIdx.x;
    if (i < n4) {
      float4 v = ((const float4*)x)[i];
      ushort4 r;
      r.x = f2b(v.x); r.y = f2b(v.y); r.z = f2b(v.z); r.w = f2b(v.w);
      ((ushort4*)xb)[i] = r;
    }
    return;
  }
  blk -= nbCvt;
  if (blk < nbZero) {  // zero hist counters
    int i = blk * 256 + threadIdx.x;
    if (i < N) cnt[i] = 0;
    return;
  }
  blk -= nbZero;  // prepack: 32 blocks, 16 per layer
  const int layer = blk >> 4;
  const float* Wl = layer ? W2l : W1l;
  const float* Wr = layer ? W2r : W1r;
  const float* bl = layer ? b2l : b1l;
  const float* br = layer ? b2r : b1r;
  unsigned short* pack = layer ? pack2 : pack1;
  float* bsum = layer ? bsum2 : bsum1;
  const int NO = layer ? NOUT : NCH;
  int tid = (blk & 15) * 256 + threadIdx.x;  // 0..4095
  int c = tid >> 9;
  int t = (tid >> 6) & 7;
  int l = tid & 63;
  int n = t * 16 + (l & 15);
  int kb = c * 32 + ((l >> 4) << 3);
  unsigned short o[8];
#pragma unroll
  for (int j = 0; j < 8; ++j) {
    int k = kb + j;
    float v = 0.f;
    if (n < NO) v = (k < 128) ? Wl[n * 128 + k] : Wr[n * 128 + (k - 128)];
    o[j] = f2b(v);
  }
  ushort4 lo, hi;
  lo.x = o[0]; lo.y = o[1]; lo.z = o[2]; lo.w = o[3];
  hi.x = o[4]; hi.y = o[5]; hi.z = o[6]; hi.w = o[7];
  *(ushort4*)(pack + (long)tid * 8) = lo;
  *(ushort4*)(pack + (long)tid * 8 + 4) = hi;
  if (tid < 128) bsum[tid] = (tid < NO) ? (bl[tid] + br[tid]) : 0.f;
}

// ---------------- CSR build (single atomic pass) ----------------

// rank[e] = arrival order of edge e at its destination; cnt accumulates degree
__global__ void k_rank(const int* __restrict__ dst, int* __restrict__ cnt,
                       int* __restrict__ rank, int E) {
  int e = blockIdx.x * blockDim.x + threadIdx.x;
  if (e < E) rank[e] = atomicAdd(&cnt[dst[e]], 1);
}

// per-1024-block exclusive scan (block-local) + block totals
__global__ void k_scan1(const int* __restrict__ cnt, int* __restrict__ off,
                        int* __restrict__ btot, int n) {
  int i = blockIdx.x * 1024 + (int)threadIdx.x;
  int v = (i < n) ? cnt[i] : 0;
  int lane = threadIdx.x & 63;
  int wv = threadIdx.x >> 6;
  int x = v;
#pragma unroll
  for (int d = 1; d < 64; d <<= 1) {
    int t = __shfl_up(x, d);
    if (lane >= d) x += t;
  }
  __shared__ int wt[16];
  if (lane == 63) wt[wv] = x;
  __syncthreads();
  if (threadIdx.x < 16) {
    int t = wt[threadIdx.x];
#pragma unroll
    for (int d = 1; d < 16; d <<= 1) {
      int u = __shfl_up(t, d);
      if (lane >= d) t += u;
    }
    wt[threadIdx.x] = t;
  }
  __syncthreads();
  int base = (wv > 0) ? wt[wv - 1] : 0;
  int incl = x + base;
  if (i < n) off[i] = incl - v;
  if (threadIdx.x == 1023) btot[blockIdx.x] = incl;
}

// one wave scans the (<=64) block totals -> bpre (exclusive)
__global__ void k_scan2(const int* __restrict__ btot, int* __restrict__ bpre,
                        int nblocks) {
  int tid = threadIdx.x;  // 64
  int v = (tid < nblocks) ? btot[tid] : 0;
  int x = v;
#pragma unroll
  for (int d = 1; d < 64; d <<= 1) {
    int t = __shfl_up(x, d);
    if (tid >= d) x += t;
  }
  if (tid < nblocks) bpre[tid] = x - v;
}

// place edges into CSR order; NO atomics (rank precomputed)
__global__ void k_place(const int* __restrict__ src, const int* __restrict__ dst,
                        const int* __restrict__ rank, const int* __restrict__ off,
                        const int* __restrict__ bpre, int* __restrict__ esrc, int E) {
  int e = blockIdx.x * blockDim.x + threadIdx.x;
  if (e < E) {
    int d = dst[e];
    esrc[off[d] + bpre[d >> 10] + rank[e]] = src[e];
  }
}

// ---------------- fused aggregate + MFMA dual-GEMM ----------------
// Block = 128 nodes. Phase 1: 16 groups of 16 lanes gather-mean bf16 rows into
// LDS A-tile [128][136] (pad 8 shorts: 16B-aligned rows, 2-way bank pattern).
// Phase 2: 4 waves x 32 rows; agg A-frags from LDS, self A-frags from global,
// B-frags from prepacked weights (L2-hot); epilogue bias(+relu) + store.
__global__ __launch_bounds__(256) void k_layer(
    const unsigned short* __restrict__ feat,  // bf16 [N][128] (x or h)
    const int* __restrict__ off, const int* __restrict__ bpre,
    const int* __restrict__ esrc,
    const unsigned short* __restrict__ pack,  // [8][8][64][8] bf16
    const float* __restrict__ bsum,           // [128]
    unsigned short* __restrict__ outb,        // bf16 out (layer1) or null
    float* __restrict__ outf,                 // f32 out (layer2) or null
    int N, int E, int NO, int do_relu) {
  __shared__ unsigned short Atile[128][136];

  const int Rb = blockIdx.x * 128;
  const int grp = threadIdx.x >> 4;         // 0..15
  const int col = (threadIdx.x & 15) * 8;   // ushort8 column

  // ---- phase 1: aggregate 128 nodes (8 chunks of 16) ----
#pragma unroll 1
  for (int chunk = 0; chunk < 8; ++chunk) {
    const int lr = chunk * 16 + grp;        // local row
    const int g = Rb + lr;                  // node id
    float acc[8];
#pragma unroll
    for (int k = 0; k < 8; ++k) acc[k] = 0.f;

    if (g < N) {
      const int b = off[g] + bpre[g >> 10];
      const int e = (g + 1 < N) ? (off[g + 1] + bpre[(g + 1) >> 10]) : E;
      const unsigned short* fcol = feat + col;
      int j = b;
      for (; j + 7 < e; j += 8) {
        const int i0 = esrc[j + 0], i1 = esrc[j + 1], i2 = esrc[j + 2], i3 = esrc[j + 3];
        const int i4 = esrc[j + 4], i5 = esrc[j + 5], i6 = esrc[j + 6], i7 = esrc[j + 7];
        const ushort8 v0 = *(const ushort8*)(fcol + (long)i0 * NCH);
        const ushort8 v1 = *(const ushort8*)(fcol + (long)i1 * NCH);
        const ushort8 v2 = *(const ushort8*)(fcol + (long)i2 * NCH);
        const ushort8 v3 = *(const ushort8*)(fcol + (long)i3 * NCH);
        const ushort8 v4 = *(const ushort8*)(fcol + (long)i4 * NCH);
        const ushort8 v5 = *(const ushort8*)(fcol + (long)i5 * NCH);
        const ushort8 v6 = *(const ushort8*)(fcol + (long)i6 * NCH);
        const ushort8 v7 = *(const ushort8*)(fcol + (long)i7 * NCH);
#pragma unroll
        for (int k = 0; k < 8; ++k) {
          acc[k] += b2f(v0[k]); acc[k] += b2f(v1[k]);
          acc[k] += b2f(v2[k]); acc[k] += b2f(v3[k]);
          acc[k] += b2f(v4[k]); acc[k] += b2f(v5[k]);
          acc[k] += b2f(v6[k]); acc[k] += b2f(v7[k]);
        }
      }
      if (j + 3 < e) {
        const int i0 = esrc[j + 0], i1 = esrc[j + 1], i2 = esrc[j + 2], i3 = esrc[j + 3];
        const ushort8 v0 = *(const ushort8*)(fcol + (long)i0 * NCH);
        const ushort8 v1 = *(const ushort8*)(fcol + (long)i1 * NCH);
        const ushort8 v2 = *(const ushort8*)(fcol + (long)i2 * NCH);
        const ushort8 v3 = *(const ushort8*)(fcol + (long)i3 * NCH);
#pragma unroll
        for (int k = 0; k < 8; ++k) {
          acc[k] += b2f(v0[k]); acc[k] += b2f(v1[k]);
          acc[k] += b2f(v2[k]); acc[k] += b2f(v3[k]);
        }
        j += 4;
      }
      for (; j < e; ++j) {
        const ushort8 v = *(const ushort8*)(fcol + (long)esrc[j] * NCH);
#pragma unroll
        for (int k = 0; k < 8; ++k) acc[k] += b2f(v[k]);
      }
      int deg = e - b;
      if (deg < 1) deg = 1;
      const float inv = 1.f / (float)deg;
#pragma unroll
      for (int k = 0; k < 8; ++k) acc[k] *= inv;
    }
    ushort8 r;
#pragma unroll
    for (int k = 0; k < 8; ++k) r[k] = f2b(acc[k]);
    *(ushort8*)&Atile[lr][col] = r;
  }
  __syncthreads();

  // ---- phase 2: dual-GEMM ----
  const int wave = threadIdx.x >> 6;
  const int lane = threadIdx.x & 63;
  const int mrow = lane & 15;
  const int koct = (lane >> 4) * 8;
  const int lr0 = wave * 32 + mrow;       // local rows
  const int lr1 = lr0 + 16;
  int gr0 = Rb + lr0; if (gr0 > N - 1) gr0 = N - 1;  // global (self) rows, clamped
  int gr1 = Rb + lr1; if (gr1 > N - 1) gr1 = N - 1;

  f32x4 acc[2][8];
#pragma unroll
  for (int mt = 0; mt < 2; ++mt)
#pragma unroll
    for (int t = 0; t < 8; ++t) acc[mt][t] = (f32x4){0.f, 0.f, 0.f, 0.f};

#pragma unroll
  for (int c = 0; c < 8; ++c) {
    const int k0 = (c & 3) * 32;
    bf16x8 a0, a1;
    if (c < 4) {  // agg part from LDS
      a0 = *(const bf16x8*)&Atile[lr0][k0 + koct];
      a1 = *(const bf16x8*)&Atile[lr1][k0 + koct];
    } else {      // self part from global
      a0 = *(const bf16x8*)(feat + (long)gr0 * NCH + k0 + koct);
      a1 = *(const bf16x8*)(feat + (long)gr1 * NCH + k0 + koct);
    }
    const unsigned short* bp = pack + ((long)(c * 8) * 64 + lane) * 8;
#pragma unroll
    for (int t = 0; t < 8; ++t) {
      const bf16x8 bfrag = *(const bf16x8*)(bp + (long)t * 512);
      acc[0][t] = __builtin_amdgcn_mfma_f32_16x16x32_bf16(a0, bfrag, acc[0][t], 0, 0, 0);
      acc[1][t] = __builtin_amdgcn_mfma_f32_16x16x32_bf16(a1, bfrag, acc[1][t], 0, 0, 0);
    }
  }

  // epilogue: C/D layout col=lane&15, row=(lane>>4)*4+reg
  const int nloc = lane & 15;
  const int rquad = (lane >> 4) * 4;
#pragma unroll
  for (int mt = 0; mt < 2; ++mt) {
#pragma unroll
    for (int t = 0; t < 8; ++t) {
      const int n = t * 16 + nloc;
      const float bias = bsum[n];
#pragma unroll
      for (int r = 0; r < 4; ++r) {
        const int m = Rb + wave * 32 + mt * 16 + rquad + r;
        if (m < N && n < NO) {
          float v = acc[mt][t][r] + bias;
          if (do_relu) v = fmaxf(v, 0.f);
          if (outb) outb[(long)m * NCH + n] = f2b(v);
          else outf[(long)m * NO + n] = v;
        }
      }
    }
  }
}

// ---------------- launch ----------------

extern "C" void kernel_launch(void* const* d_in, const int* in_sizes, int n_in,
                              void* d_out, int out_size, void* d_ws, size_t ws_size,
                              hipStream_t stream) {
  const float* x = (const float*)d_in[0];
  const int* ei = (const int*)d_in[1];
  const float* W1l = (const float*)d_in[2];
  const float* b1l = (const float*)d_in[3];
  const float* W1r = (const float*)d_in[4];
  const float* b1r = (const float*)d_in[5];
  const float* W2l = (const float*)d_in[6];
  const float* b2l = (const float*)d_in[7];
  const float* W2r = (const float*)d_in[8];
  const float* b2r = (const float*)d_in[9];
  float* out = (float*)d_out;

  const int N = in_sizes[0] / NCH;  // 40000
  const int E = in_sizes[1] / 2;    // 640000
  const int NOUT = out_size / N;    // 121

  const int* src = ei;
  const int* dst = ei + E;

  char* w = (char*)d_ws;
  auto alloc = [&](size_t bytes) {
    char* p = w;
    w += (bytes + 255) & ~(size_t)255;
    return p;
  };
  unsigned short* xb = (unsigned short*)alloc((size_t)N * NCH * 2);
  unsigned short* hb = (unsigned short*)alloc((size_t)N * NCH * 2);
  unsigned short* pack1 = (unsigned short*)alloc(8 * 8 * 64 * 8 * 2);
  unsigned short* pack2 = (unsigned short*)alloc(8 * 8 * 64 * 8 * 2);
  float* bsum1 = (float*)alloc(128 * 4);
  float* bsum2 = (float*)alloc(128 * 4);
  int* esrc = (int*)alloc((size_t)E * 4);
  int* rank = (int*)alloc((size_t)E * 4);
  int* off = (int*)alloc((size_t)N * 4);
  int* cnt = (int*)alloc((size_t)N * 4);
  int* btot = (int*)alloc(64 * 4);
  int* bpre = (int*)alloc(64 * 4);

  const int nb1024 = (N + 1023) / 1024;  // 40
  const int n4 = N * NCH / 4;
  const int nbCvt = (n4 + 255) / 256;    // 5000
  const int nbZero = (N + 255) / 256;    // 157

  // setup: convert + zero + prepack, one dispatch
  k_setup<<<nbCvt + nbZero + 32, 256, 0, stream>>>(
      x, xb, n4, cnt, N,
      W1l, W1r, b1l, b1r, W2l, W2r, b2l, b2r,
      pack1, pack2, bsum1, bsum2, NOUT, nbCvt, nbZero);

  // CSR build: one atomic pass + scan + atomic-free place
  k_rank<<<(E + 255) / 256, 256, 0, stream>>>(dst, cnt, rank, E);
  k_scan1<<<nb1024, 1024, 0, stream>>>(cnt, off, btot, N);
  k_scan2<<<1, 64, 0, stream>>>(btot, bpre, nb1024);
  k_place<<<(E + 255) / 256, 256, 0, stream>>>(src, dst, rank, off, bpre, esrc, E);

  const int gblk = (N + 127) / 128;  // 313

  // layer 1 (relu, bf16 out) ; layer 2 (f32 out)
  k_layer<<<gblk, 256, 0, stream>>>(xb, off, bpre, esrc, pack1, bsum1,
                                    hb, (float*)nullptr, N, E, NCH, 1);
  k_layer<<<gblk, 256, 0, stream>>>(hb, off, bpre, esrc, pack2, bsum2,
                                    (unsigned short*)nullptr, out, N, E, NOUT, 0);
}

// Round 6
// 210.857 us; speedup vs baseline: 1.1612x; 1.1612x over previous
//
#include <hip/hip_runtime.h>

// GraphSAGE 2-layer inference. N=40000, E=640000, C=128, OUT=121.
// R6: un-fuse R5 (fusion starved the gather phase: 313 blocks, 11% occupancy).
// Bucket-CSR: slot[node][64] filled by ONE atomic pass (no scan, no place);
// overflow list keeps exactness for any input. 6 dispatches:
//   memset(cnt,ovf_n) -> k_main(bucket || convert || prepack)
//   -> k_agg -> k_gemm -> k_agg -> k_gemm
// Aggregation stays at max grid parallelism (2500 blocks, 16 lanes/node).

#define NCH 128
#define CAP 64

typedef __bf16 bf16x8 __attribute__((ext_vector_type(8)));
typedef float f32x4 __attribute__((ext_vector_type(4)));
typedef unsigned short ushort8 __attribute__((ext_vector_type(8)));

static __device__ __forceinline__ unsigned short f2b(float f) {
  return __builtin_bit_cast(unsigned short, static_cast<__bf16>(f));
}
static __device__ __forceinline__ float b2f(unsigned short u) {
  union { unsigned int i; float f; } v;
  v.i = ((unsigned int)u) << 16;
  return v.f;
}

// ---------------- fused main: bucket CSR || x->bf16 || weight prepack ----------------
// pack[c][t][lane][j] = W'[c*32 + (lane>>4)*8 + j][t*16 + (lane&15)]
// (B-frag for mfma_f32_16x16x32_bf16: n=lane&15, k=(lane>>4)*8+j); W' = [Wl;Wr].
__global__ __launch_bounds__(256) void k_main(
    const int* __restrict__ src, const int* __restrict__ dst, int E,
    int* __restrict__ cnt, int* __restrict__ slot,
    int* __restrict__ ovf_n, int2* __restrict__ ovf,
    const float* __restrict__ x, unsigned short* __restrict__ xb, int n4,
    const float* __restrict__ W1l, const float* __restrict__ W1r,
    const float* __restrict__ b1l, const float* __restrict__ b1r,
    const float* __restrict__ W2l, const float* __restrict__ W2r,
    const float* __restrict__ b2l, const float* __restrict__ b2r,
    unsigned short* __restrict__ pack1, unsigned short* __restrict__ pack2,
    float* __restrict__ bsum1, float* __restrict__ bsum2, int NOUT,
    int nbBkt, int nbCvt) {
  int blk = blockIdx.x;
  if (blk < nbBkt) {  // bucket: one atomic per edge, src -> slot[d][rank]
    int e = blk * 256 + threadIdx.x;
    if (e < E) {
      int d = dst[e];
      int pos = atomicAdd(&cnt[d], 1);
      if (pos < CAP) slot[(long)d * CAP + pos] = src[e];
      else {
        int o = atomicAdd(ovf_n, 1);
        ovf[o] = make_int2(d, src[e]);
      }
    }
    return;
  }
  blk -= nbBkt;
  if (blk < nbCvt) {  // fp32 -> bf16 convert
    int i = blk * 256 + threadIdx.x;
    if (i < n4) {
      float4 v = ((const float4*)x)[i];
      ushort4 r;
      r.x = f2b(v.x); r.y = f2b(v.y); r.z = f2b(v.z); r.w = f2b(v.w);
      ((ushort4*)xb)[i] = r;
    }
    return;
  }
  blk -= nbCvt;  // prepack: 32 blocks, 16 per layer
  const int layer = blk >> 4;
  const float* Wl = layer ? W2l : W1l;
  const float* Wr = layer ? W2r : W1r;
  const float* bl = layer ? b2l : b1l;
  const float* br = layer ? b2r : b1r;
  unsigned short* pack = layer ? pack2 : pack1;
  float* bsum = layer ? bsum2 : bsum1;
  const int NO = layer ? NOUT : NCH;
  int tid = (blk & 15) * 256 + threadIdx.x;  // 0..4095
  int c = tid >> 9;
  int t = (tid >> 6) & 7;
  int l = tid & 63;
  int n = t * 16 + (l & 15);
  int kb = c * 32 + ((l >> 4) << 3);
  unsigned short o[8];
#pragma unroll
  for (int j = 0; j < 8; ++j) {
    int k = kb + j;
    float v = 0.f;
    if (n < NO) v = (k < 128) ? Wl[n * 128 + k] : Wr[n * 128 + (k - 128)];
    o[j] = f2b(v);
  }
  ushort4 lo, hi;
  lo.x = o[0]; lo.y = o[1]; lo.z = o[2]; lo.w = o[3];
  hi.x = o[4]; hi.y = o[5]; hi.z = o[6]; hi.w = o[7];
  *(ushort4*)(pack + (long)tid * 8) = lo;
  *(ushort4*)(pack + (long)tid * 8 + 4) = hi;
  if (tid < 128) bsum[tid] = (tid < NO) ? (bl[tid] + br[tid]) : 0.f;
}

// ---------------- mean aggregation (bf16 gather, fp32 accum) ----------------
// 16 lanes per node, ushort8 (16B) per lane covers the 256B bf16 row;
// 8-deep unroll -> 8 x 16B outstanding loads per lane. Edge indices come
// from the node's contiguous slot row (broadcast within the 16-lane group).
__global__ __launch_bounds__(256) void k_agg(
    const unsigned short* __restrict__ feat, const int* __restrict__ cnt,
    const int* __restrict__ slot, const int* __restrict__ ovf_n,
    const int2* __restrict__ ovf, unsigned short* __restrict__ agg, int N) {
  const int g = (blockIdx.x * 256 + (int)threadIdx.x) >> 4;  // node
  if (g >= N) return;
  const int col = (threadIdx.x & 15) * 8;

  const int deg = cnt[g];
  const int m = (deg < CAP) ? deg : CAP;
  const int* __restrict__ sl = slot + (long)g * CAP;
  const unsigned short* fcol = feat + col;

  float acc[8];
#pragma unroll
  for (int k = 0; k < 8; ++k) acc[k] = 0.f;

  int j = 0;
  for (; j + 7 < m; j += 8) {
    const int i0 = sl[j + 0], i1 = sl[j + 1], i2 = sl[j + 2], i3 = sl[j + 3];
    const int i4 = sl[j + 4], i5 = sl[j + 5], i6 = sl[j + 6], i7 = sl[j + 7];
    const ushort8 v0 = *(const ushort8*)(fcol + (long)i0 * NCH);
    const ushort8 v1 = *(const ushort8*)(fcol + (long)i1 * NCH);
    const ushort8 v2 = *(const ushort8*)(fcol + (long)i2 * NCH);
    const ushort8 v3 = *(const ushort8*)(fcol + (long)i3 * NCH);
    const ushort8 v4 = *(const ushort8*)(fcol + (long)i4 * NCH);
    const ushort8 v5 = *(const ushort8*)(fcol + (long)i5 * NCH);
    const ushort8 v6 = *(const ushort8*)(fcol + (long)i6 * NCH);
    const ushort8 v7 = *(const ushort8*)(fcol + (long)i7 * NCH);
#pragma unroll
    for (int k = 0; k < 8; ++k) {
      acc[k] += b2f(v0[k]); acc[k] += b2f(v1[k]);
      acc[k] += b2f(v2[k]); acc[k] += b2f(v3[k]);
      acc[k] += b2f(v4[k]); acc[k] += b2f(v5[k]);
      acc[k] += b2f(v6[k]); acc[k] += b2f(v7[k]);
    }
  }
  if (j + 3 < m) {
    const int i0 = sl[j + 0], i1 = sl[j + 1], i2 = sl[j + 2], i3 = sl[j + 3];
    const ushort8 v0 = *(const ushort8*)(fcol + (long)i0 * NCH);
    const ushort8 v1 = *(const ushort8*)(fcol + (long)i1 * NCH);
    const ushort8 v2 = *(const ushort8*)(fcol + (long)i2 * NCH);
    const ushort8 v3 = *(const ushort8*)(fcol + (long)i3 * NCH);
#pragma unroll
    for (int k = 0; k < 8; ++k) {
      acc[k] += b2f(v0[k]); acc[k] += b2f(v1[k]);
      acc[k] += b2f(v2[k]); acc[k] += b2f(v3[k]);
    }
    j += 4;
  }
  for (; j < m; ++j) {
    const ushort8 v = *(const ushort8*)(fcol + (long)sl[j] * NCH);
#pragma unroll
    for (int k = 0; k < 8; ++k) acc[k] += b2f(v[k]);
  }

  // overflow pass (normally empty; keeps exactness for any input)
  const int on = *ovf_n;
  for (int o = 0; o < on; ++o) {
    const int2 p = ovf[o];
    if (p.x == g) {
      const ushort8 v = *(const ushort8*)(fcol + (long)p.y * NCH);
#pragma unroll
      for (int k = 0; k < 8; ++k) acc[k] += b2f(v[k]);
    }
  }

  int dd = (deg < 1) ? 1 : deg;
  const float inv = 1.f / (float)dd;
  ushort8 r;
#pragma unroll
  for (int k = 0; k < 8; ++k) r[k] = f2b(acc[k] * inv);
  *(ushort8*)(agg + (long)g * NCH + col) = r;
}

// ---------------- MFMA dual-GEMM ----------------
// out[m][n] = relu?( sum_k agg[m][k]Wl[n][k] + self[m][k]Wr[n][k] + bias[n] )
// LDS-free: wave = 32 rows x 128 cols; K'=256 in 8 chunks; A-frags from
// global bf16 (16B/lane), B-frags from prepacked weights (L2-hot, 64KB).
__global__ __launch_bounds__(256) void k_gemm(
    const unsigned short* __restrict__ Ag,   // agg  bf16 [M][128]
    const unsigned short* __restrict__ Sf,   // self bf16 [M][128]
    const unsigned short* __restrict__ pack, // [8][8][64][8] bf16
    const float* __restrict__ bsum,          // [128]
    unsigned short* __restrict__ outb,       // bf16 out (layer1) or null
    float* __restrict__ outf,                // f32 out (layer2) or null
    int M, int NO, int do_relu) {
  const int wave = threadIdx.x >> 6;
  const int lane = threadIdx.x & 63;
  const int R = blockIdx.x * 128 + wave * 32;  // 2 m-tiles: R, R+16
  const int mrow = lane & 15;
  const int koct = (lane >> 4) * 8;

  int r0 = R + mrow;       if (r0 > M - 1) r0 = M - 1;
  int r1 = R + 16 + mrow;  if (r1 > M - 1) r1 = M - 1;

  f32x4 acc[2][8];
#pragma unroll
  for (int mt = 0; mt < 2; ++mt)
#pragma unroll
    for (int t = 0; t < 8; ++t) acc[mt][t] = (f32x4){0.f, 0.f, 0.f, 0.f};

#pragma unroll
  for (int c = 0; c < 8; ++c) {
    const unsigned short* __restrict__ Abase = (c < 4) ? Ag : Sf;
    const int k0 = (c & 3) * 32;
    const bf16x8 a0 = *(const bf16x8*)(Abase + (long)r0 * NCH + k0 + koct);
    const bf16x8 a1 = *(const bf16x8*)(Abase + (long)r1 * NCH + k0 + koct);
    const unsigned short* bp = pack + ((long)(c * 8) * 64 + lane) * 8;
#pragma unroll
    for (int t = 0; t < 8; ++t) {
      const bf16x8 bfrag = *(const bf16x8*)(bp + (long)t * 512);
      acc[0][t] = __builtin_amdgcn_mfma_f32_16x16x32_bf16(a0, bfrag, acc[0][t], 0, 0, 0);
      acc[1][t] = __builtin_amdgcn_mfma_f32_16x16x32_bf16(a1, bfrag, acc[1][t], 0, 0, 0);
    }
  }

  // epilogue: C/D layout col=lane&15, row=(lane>>4)*4+reg
  const int nloc = lane & 15;
  const int rquad = (lane >> 4) * 4;
#pragma unroll
  for (int mt = 0; mt < 2; ++mt) {
#pragma unroll
    for (int t = 0; t < 8; ++t) {
      const int n = t * 16 + nloc;
      const float bias = bsum[n];
#pragma unroll
      for (int r = 0; r < 4; ++r) {
        const int m = R + mt * 16 + rquad + r;
        if (m < M && n < NO) {
          float v = acc[mt][t][r] + bias;
          if (do_relu) v = fmaxf(v, 0.f);
          if (outb) outb[(long)m * NCH + n] = f2b(v);
          else outf[(long)m * NO + n] = v;
        }
      }
    }
  }
}

// ---------------- launch ----------------

extern "C" void kernel_launch(void* const* d_in, const int* in_sizes, int n_in,
                              void* d_out, int out_size, void* d_ws, size_t ws_size,
                              hipStream_t stream) {
  const float* x = (const float*)d_in[0];
  const int* ei = (const int*)d_in[1];
  const float* W1l = (const float*)d_in[2];
  const float* b1l = (const float*)d_in[3];
  const float* W1r = (const float*)d_in[4];
  const float* b1r = (const float*)d_in[5];
  const float* W2l = (const float*)d_in[6];
  const float* b2l = (const float*)d_in[7];
  const float* W2r = (const float*)d_in[8];
  const float* b2r = (const float*)d_in[9];
  float* out = (float*)d_out;

  const int N = in_sizes[0] / NCH;  // 40000
  const int E = in_sizes[1] / 2;    // 640000
  const int NOUT = out_size / N;    // 121

  const int* src = ei;
  const int* dst = ei + E;

  char* w = (char*)d_ws;
  auto alloc = [&](size_t bytes) {
    char* p = w;
    w += (bytes + 255) & ~(size_t)255;
    return p;
  };
  unsigned short* xb = (unsigned short*)alloc((size_t)N * NCH * 2);
  unsigned short* hb = (unsigned short*)alloc((size_t)N * NCH * 2);
  unsigned short* aggb = (unsigned short*)alloc((size_t)N * NCH * 2);
  unsigned short* pack1 = (unsigned short*)alloc(8 * 8 * 64 * 8 * 2);
  unsigned short* pack2 = (unsigned short*)alloc(8 * 8 * 64 * 8 * 2);
  float* bsum1 = (float*)alloc(128 * 4);
  float* bsum2 = (float*)alloc(128 * 4);
  int* cnt = (int*)alloc((size_t)(N + 1) * 4);  // [cnt(N) | ovf_n(1)]
  int* ovf_n = cnt + N;
  int* slot = (int*)alloc((size_t)N * CAP * 4);
  int2* ovf = (int2*)alloc((size_t)E * 8);

  const int n4 = N * NCH / 4;
  const int nbBkt = (E + 255) / 256;   // 2500
  const int nbCvt = (n4 + 255) / 256;  // 5000

  // zero degree counters + overflow count (one memset node)
  hipMemsetAsync(cnt, 0, (size_t)(N + 1) * 4, stream);

  // bucket || convert || prepack in one dispatch
  k_main<<<nbBkt + nbCvt + 32, 256, 0, stream>>>(
      src, dst, E, cnt, slot, ovf_n, ovf,
      x, xb, n4,
      W1l, W1r, b1l, b1r, W2l, W2r, b2l, b2r,
      pack1, pack2, bsum1, bsum2, NOUT, nbBkt, nbCvt);

  const int gaggr = (N * 16 + 255) / 256;  // 2500
  const int gblk = (N + 127) / 128;        // 313

  // layer 1 (relu, bf16 out)
  k_agg<<<gaggr, 256, 0, stream>>>(xb, cnt, slot, ovf_n, ovf, aggb, N);
  k_gemm<<<gblk, 256, 0, stream>>>(aggb, xb, pack1, bsum1, hb, (float*)nullptr,
                                   N, NCH, 1);
  // layer 2 (f32 out)
  k_agg<<<gaggr, 256, 0, stream>>>(hb, cnt, slot, ovf_n, ovf, aggb, N);
  k_gemm<<<gblk, 256, 0, stream>>>(aggb, hb, pack2, bsum2, (unsigned short*)nullptr,
                                   out, N, NOUT, 0);
}

// Round 7
// 210.395 us; speedup vs baseline: 1.1637x; 1.0022x over previous
//
#include <hip/hip_runtime.h>

// GraphSAGE 2-layer inference. N=40000, E=640000, C=128, OUT=121.
// R7 = R6 + atomic-contention fix: degree counters padded to one per 64B
// cache line (stride 16 ints). R6 profile: k_main 46us, VALUBusy 0.8% ->
// ~256 same-line atomics serialized per 64B line (16 counters/line x avg
// degree 16). Padding cuts per-line atomics to ~16.
// 6 dispatches: memset -> k_main(bucket||convert||prepack) -> agg -> gemm -> agg -> gemm.

#define NCH 128
#define CAP 64
#define CSTR 16  // cnt stride in ints: one counter per 64B line

typedef __bf16 bf16x8 __attribute__((ext_vector_type(8)));
typedef float f32x4 __attribute__((ext_vector_type(4)));
typedef unsigned short ushort8 __attribute__((ext_vector_type(8)));

static __device__ __forceinline__ unsigned short f2b(float f) {
  return __builtin_bit_cast(unsigned short, static_cast<__bf16>(f));
}
static __device__ __forceinline__ float b2f(unsigned short u) {
  union { unsigned int i; float f; } v;
  v.i = ((unsigned int)u) << 16;
  return v.f;
}

// ---------------- fused main: bucket CSR || x->bf16 || weight prepack ----------------
// pack[c][t][lane][j] = W'[c*32 + (lane>>4)*8 + j][t*16 + (lane&15)]
// (B-frag for mfma_f32_16x16x32_bf16: n=lane&15, k=(lane>>4)*8+j); W' = [Wl;Wr].
__global__ __launch_bounds__(256) void k_main(
    const int* __restrict__ src, const int* __restrict__ dst, int E,
    int* __restrict__ cnt, int* __restrict__ slot,
    int* __restrict__ ovf_n, int2* __restrict__ ovf,
    const float* __restrict__ x, unsigned short* __restrict__ xb, int n4,
    const float* __restrict__ W1l, const float* __restrict__ W1r,
    const float* __restrict__ b1l, const float* __restrict__ b1r,
    const float* __restrict__ W2l, const float* __restrict__ W2r,
    const float* __restrict__ b2l, const float* __restrict__ b2r,
    unsigned short* __restrict__ pack1, unsigned short* __restrict__ pack2,
    float* __restrict__ bsum1, float* __restrict__ bsum2, int NOUT,
    int nbBkt, int nbCvt) {
  int blk = blockIdx.x;
  if (blk < nbBkt) {  // bucket: one atomic per edge, src -> slot[d][rank]
    int e = blk * 256 + threadIdx.x;
    if (e < E) {
      int d = dst[e];
      int s = src[e];
      int pos = atomicAdd(&cnt[(long)d * CSTR], 1);
      if (pos < CAP) slot[(long)d * CAP + pos] = s;
      else {
        int o = atomicAdd(ovf_n, 1);
        ovf[o] = make_int2(d, s);
      }
    }
    return;
  }
  blk -= nbBkt;
  if (blk < nbCvt) {  // fp32 -> bf16 convert
    int i = blk * 256 + threadIdx.x;
    if (i < n4) {
      float4 v = ((const float4*)x)[i];
      ushort4 r;
      r.x = f2b(v.x); r.y = f2b(v.y); r.z = f2b(v.z); r.w = f2b(v.w);
      ((ushort4*)xb)[i] = r;
    }
    return;
  }
  blk -= nbCvt;  // prepack: 32 blocks, 16 per layer
  const int layer = blk >> 4;
  const float* Wl = layer ? W2l : W1l;
  const float* Wr = layer ? W2r : W1r;
  const float* bl = layer ? b2l : b1l;
  const float* br = layer ? b2r : b1r;
  unsigned short* pack = layer ? pack2 : pack1;
  float* bsum = layer ? bsum2 : bsum1;
  const int NO = layer ? NOUT : NCH;
  int tid = (blk & 15) * 256 + threadIdx.x;  // 0..4095
  int c = tid >> 9;
  int t = (tid >> 6) & 7;
  int l = tid & 63;
  int n = t * 16 + (l & 15);
  int kb = c * 32 + ((l >> 4) << 3);
  unsigned short o[8];
#pragma unroll
  for (int j = 0; j < 8; ++j) {
    int k = kb + j;
    float v = 0.f;
    if (n < NO) v = (k < 128) ? Wl[n * 128 + k] : Wr[n * 128 + (k - 128)];
    o[j] = f2b(v);
  }
  ushort4 lo, hi;
  lo.x = o[0]; lo.y = o[1]; lo.z = o[2]; lo.w = o[3];
  hi.x = o[4]; hi.y = o[5]; hi.z = o[6]; hi.w = o[7];
  *(ushort4*)(pack + (long)tid * 8) = lo;
  *(ushort4*)(pack + (long)tid * 8 + 4) = hi;
  if (tid < 128) bsum[tid] = (tid < NO) ? (bl[tid] + br[tid]) : 0.f;
}

// ---------------- mean aggregation (bf16 gather, fp32 accum) ----------------
// 16 lanes per node, ushort8 (16B) per lane covers the 256B bf16 row;
// 8-deep unroll -> 8 x 16B outstanding loads per lane.
__global__ __launch_bounds__(256) void k_agg(
    const unsigned short* __restrict__ feat, const int* __restrict__ cnt,
    const int* __restrict__ slot, const int* __restrict__ ovf_n,
    const int2* __restrict__ ovf, unsigned short* __restrict__ agg, int N) {
  const int g = (blockIdx.x * 256 + (int)threadIdx.x) >> 4;  // node
  if (g >= N) return;
  const int col = (threadIdx.x & 15) * 8;

  const int deg = cnt[(long)g * CSTR];
  const int m = (deg < CAP) ? deg : CAP;
  const int* __restrict__ sl = slot + (long)g * CAP;
  const unsigned short* fcol = feat + col;

  float acc[8];
#pragma unroll
  for (int k = 0; k < 8; ++k) acc[k] = 0.f;

  int j = 0;
  for (; j + 7 < m; j += 8) {
    const int i0 = sl[j + 0], i1 = sl[j + 1], i2 = sl[j + 2], i3 = sl[j + 3];
    const int i4 = sl[j + 4], i5 = sl[j + 5], i6 = sl[j + 6], i7 = sl[j + 7];
    const ushort8 v0 = *(const ushort8*)(fcol + (long)i0 * NCH);
    const ushort8 v1 = *(const ushort8*)(fcol + (long)i1 * NCH);
    const ushort8 v2 = *(const ushort8*)(fcol + (long)i2 * NCH);
    const ushort8 v3 = *(const ushort8*)(fcol + (long)i3 * NCH);
    const ushort8 v4 = *(const ushort8*)(fcol + (long)i4 * NCH);
    const ushort8 v5 = *(const ushort8*)(fcol + (long)i5 * NCH);
    const ushort8 v6 = *(const ushort8*)(fcol + (long)i6 * NCH);
    const ushort8 v7 = *(const ushort8*)(fcol + (long)i7 * NCH);
#pragma unroll
    for (int k = 0; k < 8; ++k) {
      acc[k] += b2f(v0[k]); acc[k] += b2f(v1[k]);
      acc[k] += b2f(v2[k]); acc[k] += b2f(v3[k]);
      acc[k] += b2f(v4[k]); acc[k] += b2f(v5[k]);
      acc[k] += b2f(v6[k]); acc[k] += b2f(v7[k]);
    }
  }
  if (j + 3 < m) {
    const int i0 = sl[j + 0], i1 = sl[j + 1], i2 = sl[j + 2], i3 = sl[j + 3];
    const ushort8 v0 = *(const ushort8*)(fcol + (long)i0 * NCH);
    const ushort8 v1 = *(const ushort8*)(fcol + (long)i1 * NCH);
    const ushort8 v2 = *(const ushort8*)(fcol + (long)i2 * NCH);
    const ushort8 v3 = *(const ushort8*)(fcol + (long)i3 * NCH);
#pragma unroll
    for (int k = 0; k < 8; ++k) {
      acc[k] += b2f(v0[k]); acc[k] += b2f(v1[k]);
      acc[k] += b2f(v2[k]); acc[k] += b2f(v3[k]);
    }
    j += 4;
  }
  for (; j < m; ++j) {
    const ushort8 v = *(const ushort8*)(fcol + (long)sl[j] * NCH);
#pragma unroll
    for (int k = 0; k < 8; ++k) acc[k] += b2f(v[k]);
  }

  // overflow pass (normally empty; keeps exactness for any input)
  const int on = *ovf_n;
  for (int o = 0; o < on; ++o) {
    const int2 p = ovf[o];
    if (p.x == g) {
      const ushort8 v = *(const ushort8*)(fcol + (long)p.y * NCH);
#pragma unroll
      for (int k = 0; k < 8; ++k) acc[k] += b2f(v[k]);
    }
  }

  int dd = (deg < 1) ? 1 : deg;
  const float inv = 1.f / (float)dd;
  ushort8 r;
#pragma unroll
  for (int k = 0; k < 8; ++k) r[k] = f2b(acc[k] * inv);
  *(ushort8*)(agg + (long)g * NCH + col) = r;
}

// ---------------- MFMA dual-GEMM ----------------
// out[m][n] = relu?( sum_k agg[m][k]Wl[n][k] + self[m][k]Wr[n][k] + bias[n] )
// LDS-free: wave = 32 rows x 128 cols; K'=256 in 8 chunks; A-frags from
// global bf16 (16B/lane), B-frags from prepacked weights (L2-hot, 64KB).
__global__ __launch_bounds__(256) void k_gemm(
    const unsigned short* __restrict__ Ag,   // agg  bf16 [M][128]
    const unsigned short* __restrict__ Sf,   // self bf16 [M][128]
    const unsigned short* __restrict__ pack, // [8][8][64][8] bf16
    const float* __restrict__ bsum,          // [128]
    unsigned short* __restrict__ outb,       // bf16 out (layer1) or null
    float* __restrict__ outf,                // f32 out (layer2) or null
    int M, int NO, int do_relu) {
  const int wave = threadIdx.x >> 6;
  const int lane = threadIdx.x & 63;
  const int R = blockIdx.x * 128 + wave * 32;  // 2 m-tiles: R, R+16
  const int mrow = lane & 15;
  const int koct = (lane >> 4) * 8;

  int r0 = R + mrow;       if (r0 > M - 1) r0 = M - 1;
  int r1 = R + 16 + mrow;  if (r1 > M - 1) r1 = M - 1;

  f32x4 acc[2][8];
#pragma unroll
  for (int mt = 0; mt < 2; ++mt)
#pragma unroll
    for (int t = 0; t < 8; ++t) acc[mt][t] = (f32x4){0.f, 0.f, 0.f, 0.f};

#pragma unroll
  for (int c = 0; c < 8; ++c) {
    const unsigned short* __restrict__ Abase = (c < 4) ? Ag : Sf;
    const int k0 = (c & 3) * 32;
    const bf16x8 a0 = *(const bf16x8*)(Abase + (long)r0 * NCH + k0 + koct);
    const bf16x8 a1 = *(const bf16x8*)(Abase + (long)r1 * NCH + k0 + koct);
    const unsigned short* bp = pack + ((long)(c * 8) * 64 + lane) * 8;
#pragma unroll
    for (int t = 0; t < 8; ++t) {
      const bf16x8 bfrag = *(const bf16x8*)(bp + (long)t * 512);
      acc[0][t] = __builtin_amdgcn_mfma_f32_16x16x32_bf16(a0, bfrag, acc[0][t], 0, 0, 0);
      acc[1][t] = __builtin_amdgcn_mfma_f32_16x16x32_bf16(a1, bfrag, acc[1][t], 0, 0, 0);
    }
  }

  // epilogue: C/D layout col=lane&15, row=(lane>>4)*4+reg
  const int nloc = lane & 15;
  const int rquad = (lane >> 4) * 4;
#pragma unroll
  for (int mt = 0; mt < 2; ++mt) {
#pragma unroll
    for (int t = 0; t < 8; ++t) {
      const int n = t * 16 + nloc;
      const float bias = bsum[n];
#pragma unroll
      for (int r = 0; r < 4; ++r) {
        const int m = R + mt * 16 + rquad + r;
        if (m < M && n < NO) {
          float v = acc[mt][t][r] + bias;
          if (do_relu) v = fmaxf(v, 0.f);
          if (outb) outb[(long)m * NCH + n] = f2b(v);
          else outf[(long)m * NO + n] = v;
        }
      }
    }
  }
}

// ---------------- launch ----------------

extern "C" void kernel_launch(void* const* d_in, const int* in_sizes, int n_in,
                              void* d_out, int out_size, void* d_ws, size_t ws_size,
                              hipStream_t stream) {
  const float* x = (const float*)d_in[0];
  const int* ei = (const int*)d_in[1];
  const float* W1l = (const float*)d_in[2];
  const float* b1l = (const float*)d_in[3];
  const float* W1r = (const float*)d_in[4];
  const float* b1r = (const float*)d_in[5];
  const float* W2l = (const float*)d_in[6];
  const float* b2l = (const float*)d_in[7];
  const float* W2r = (const float*)d_in[8];
  const float* b2r = (const float*)d_in[9];
  float* out = (float*)d_out;

  const int N = in_sizes[0] / NCH;  // 40000
  const int E = in_sizes[1] / 2;    // 640000
  const int NOUT = out_size / N;    // 121

  const int* src = ei;
  const int* dst = ei + E;

  char* w = (char*)d_ws;
  auto alloc = [&](size_t bytes) {
    char* p = w;
    w += (bytes + 255) & ~(size_t)255;
    return p;
  };
  unsigned short* xb = (unsigned short*)alloc((size_t)N * NCH * 2);
  unsigned short* hb = (unsigned short*)alloc((size_t)N * NCH * 2);
  unsigned short* aggb = (unsigned short*)alloc((size_t)N * NCH * 2);
  unsigned short* pack1 = (unsigned short*)alloc(8 * 8 * 64 * 8 * 2);
  unsigned short* pack2 = (unsigned short*)alloc(8 * 8 * 64 * 8 * 2);
  float* bsum1 = (float*)alloc(128 * 4);
  float* bsum2 = (float*)alloc(128 * 4);
  int* cnt = (int*)alloc(((size_t)N * CSTR + 1) * 4);  // padded: 1 counter / 64B line
  int* ovf_n = cnt + (size_t)N * CSTR;
  int* slot = (int*)alloc((size_t)N * CAP * 4);
  int2* ovf = (int2*)alloc((size_t)E * 8);

  const int n4 = N * NCH / 4;
  const int nbBkt = (E + 255) / 256;   // 2500
  const int nbCvt = (n4 + 255) / 256;  // 5000

  // zero degree counters + overflow count
  hipMemsetAsync(cnt, 0, ((size_t)N * CSTR + 1) * 4, stream);

  // bucket || convert || prepack in one dispatch
  k_main<<<nbBkt + nbCvt + 32, 256, 0, stream>>>(
      src, dst, E, cnt, slot, ovf_n, ovf,
      x, xb, n4,
      W1l, W1r, b1l, b1r, W2l, W2r, b2l, b2r,
      pack1, pack2, bsum1, bsum2, NOUT, nbBkt, nbCvt);

  const int gaggr = (N * 16 + 255) / 256;  // 2500
  const int gblk = (N + 127) / 128;        // 313

  // layer 1 (relu, bf16 out)
  k_agg<<<gaggr, 256, 0, stream>>>(xb, cnt, slot, ovf_n, ovf, aggb, N);
  k_gemm<<<gblk, 256, 0, stream>>>(aggb, xb, pack1, bsum1, hb, (float*)nullptr,
                                   N, NCH, 1);
  // layer 2 (f32 out)
  k_agg<<<gaggr, 256, 0, stream>>>(hb, cnt, slot, ovf_n, ovf, aggb, N);
  k_gemm<<<gblk, 256, 0, stream>>>(aggb, hb, pack2, bsum2, (unsigned short*)nullptr,
                                   out, N, NOUT, 0);
}

// Round 8
// 210.243 us; speedup vs baseline: 1.1645x; 1.0007x over previous
//
#include <hip/hip_runtime.h>

// GraphSAGE 2-layer inference. N=40000, E=640000, C=128, OUT=121.
// R8: bucket pass software-pipelined 8 edges/thread (R7 falsified the
// contention theory: padding changed nothing -> the pass is scattered-
// transaction latency-bound with 1 op in flight/lane; same fix as R1->R2
// gather: 8 independent atomics then 8 independent stores in flight).
// CSTR reverted to 1. 6 dispatches:
// memset -> k_main(bucket||convert||prepack) -> agg -> gemm -> agg -> gemm.

#define NCH 128
#define CAP 64
#define EPT 8  // edges per thread in bucket phase

typedef __bf16 bf16x8 __attribute__((ext_vector_type(8)));
typedef float f32x4 __attribute__((ext_vector_type(4)));
typedef unsigned short ushort8 __attribute__((ext_vector_type(8)));

static __device__ __forceinline__ unsigned short f2b(float f) {
  return __builtin_bit_cast(unsigned short, static_cast<__bf16>(f));
}
static __device__ __forceinline__ float b2f(unsigned short u) {
  union { unsigned int i; float f; } v;
  v.i = ((unsigned int)u) << 16;
  return v.f;
}

// ---------------- fused main: bucket CSR || x->bf16 || weight prepack ----------------
// pack[c][t][lane][j] = W'[c*32 + (lane>>4)*8 + j][t*16 + (lane&15)]
// (B-frag for mfma_f32_16x16x32_bf16: n=lane&15, k=(lane>>4)*8+j); W' = [Wl;Wr].
__global__ __launch_bounds__(256) void k_main(
    const int* __restrict__ src, const int* __restrict__ dst, int E,
    int* __restrict__ cnt, int* __restrict__ slot,
    int* __restrict__ ovf_n, int2* __restrict__ ovf,
    const float* __restrict__ x, unsigned short* __restrict__ xb, int n4,
    const float* __restrict__ W1l, const float* __restrict__ W1r,
    const float* __restrict__ b1l, const float* __restrict__ b1r,
    const float* __restrict__ W2l, const float* __restrict__ W2r,
    const float* __restrict__ b2l, const float* __restrict__ b2r,
    unsigned short* __restrict__ pack1, unsigned short* __restrict__ pack2,
    float* __restrict__ bsum1, float* __restrict__ bsum2, int NOUT,
    int nbBkt, int nbCvt) {
  int blk = blockIdx.x;
  if (blk < nbBkt) {  // bucket: 8 edges/thread, pipelined
    const int base = blk * (256 * EPT) + (int)threadIdx.x;
    int d[EPT], s[EPT], pos[EPT];
#pragma unroll
    for (int j = 0; j < EPT; ++j) {
      const int e = base + j * 256;
      const bool ok = e < E;
      d[j] = ok ? dst[e] : -1;
      s[j] = ok ? src[e] : 0;
    }
#pragma unroll
    for (int j = 0; j < EPT; ++j)
      pos[j] = (d[j] >= 0) ? atomicAdd(&cnt[d[j]], 1) : 0;
#pragma unroll
    for (int j = 0; j < EPT; ++j) {
      if (d[j] >= 0) {
        if (pos[j] < CAP) slot[(long)d[j] * CAP + pos[j]] = s[j];
        else {
          int o = atomicAdd(ovf_n, 1);
          ovf[o] = make_int2(d[j], s[j]);
        }
      }
    }
    return;
  }
  blk -= nbBkt;
  if (blk < nbCvt) {  // fp32 -> bf16 convert
    int i = blk * 256 + threadIdx.x;
    if (i < n4) {
      float4 v = ((const float4*)x)[i];
      ushort4 r;
      r.x = f2b(v.x); r.y = f2b(v.y); r.z = f2b(v.z); r.w = f2b(v.w);
      ((ushort4*)xb)[i] = r;
    }
    return;
  }
  blk -= nbCvt;  // prepack: 32 blocks, 16 per layer
  const int layer = blk >> 4;
  const float* Wl = layer ? W2l : W1l;
  const float* Wr = layer ? W2r : W1r;
  const float* bl = layer ? b2l : b1l;
  const float* br = layer ? b2r : b1r;
  unsigned short* pack = layer ? pack2 : pack1;
  float* bsum = layer ? bsum2 : bsum1;
  const int NO = layer ? NOUT : NCH;
  int tid = (blk & 15) * 256 + threadIdx.x;  // 0..4095
  int c = tid >> 9;
  int t = (tid >> 6) & 7;
  int l = tid & 63;
  int n = t * 16 + (l & 15);
  int kb = c * 32 + ((l >> 4) << 3);
  unsigned short o[8];
#pragma unroll
  for (int j = 0; j < 8; ++j) {
    int k = kb + j;
    float v = 0.f;
    if (n < NO) v = (k < 128) ? Wl[n * 128 + k] : Wr[n * 128 + (k - 128)];
    o[j] = f2b(v);
  }
  ushort4 lo, hi;
  lo.x = o[0]; lo.y = o[1]; lo.z = o[2]; lo.w = o[3];
  hi.x = o[4]; hi.y = o[5]; hi.z = o[6]; hi.w = o[7];
  *(ushort4*)(pack + (long)tid * 8) = lo;
  *(ushort4*)(pack + (long)tid * 8 + 4) = hi;
  if (tid < 128) bsum[tid] = (tid < NO) ? (bl[tid] + br[tid]) : 0.f;
}

// ---------------- mean aggregation (bf16 gather, fp32 accum) ----------------
// 16 lanes per node, ushort8 (16B) per lane covers the 256B bf16 row;
// 8-deep unroll -> 8 x 16B outstanding loads per lane.
__global__ __launch_bounds__(256) void k_agg(
    const unsigned short* __restrict__ feat, const int* __restrict__ cnt,
    const int* __restrict__ slot, const int* __restrict__ ovf_n,
    const int2* __restrict__ ovf, unsigned short* __restrict__ agg, int N) {
  const int g = (blockIdx.x * 256 + (int)threadIdx.x) >> 4;  // node
  if (g >= N) return;
  const int col = (threadIdx.x & 15) * 8;

  const int deg = cnt[g];
  const int m = (deg < CAP) ? deg : CAP;
  const int* __restrict__ sl = slot + (long)g * CAP;
  const unsigned short* fcol = feat + col;

  float acc[8];
#pragma unroll
  for (int k = 0; k < 8; ++k) acc[k] = 0.f;

  int j = 0;
  for (; j + 7 < m; j += 8) {
    const int i0 = sl[j + 0], i1 = sl[j + 1], i2 = sl[j + 2], i3 = sl[j + 3];
    const int i4 = sl[j + 4], i5 = sl[j + 5], i6 = sl[j + 6], i7 = sl[j + 7];
    const ushort8 v0 = *(const ushort8*)(fcol + (long)i0 * NCH);
    const ushort8 v1 = *(const ushort8*)(fcol + (long)i1 * NCH);
    const ushort8 v2 = *(const ushort8*)(fcol + (long)i2 * NCH);
    const ushort8 v3 = *(const ushort8*)(fcol + (long)i3 * NCH);
    const ushort8 v4 = *(const ushort8*)(fcol + (long)i4 * NCH);
    const ushort8 v5 = *(const ushort8*)(fcol + (long)i5 * NCH);
    const ushort8 v6 = *(const ushort8*)(fcol + (long)i6 * NCH);
    const ushort8 v7 = *(const ushort8*)(fcol + (long)i7 * NCH);
#pragma unroll
    for (int k = 0; k < 8; ++k) {
      acc[k] += b2f(v0[k]); acc[k] += b2f(v1[k]);
      acc[k] += b2f(v2[k]); acc[k] += b2f(v3[k]);
      acc[k] += b2f(v4[k]); acc[k] += b2f(v5[k]);
      acc[k] += b2f(v6[k]); acc[k] += b2f(v7[k]);
    }
  }
  if (j + 3 < m) {
    const int i0 = sl[j + 0], i1 = sl[j + 1], i2 = sl[j + 2], i3 = sl[j + 3];
    const ushort8 v0 = *(const ushort8*)(fcol + (long)i0 * NCH);
    const ushort8 v1 = *(const ushort8*)(fcol + (long)i1 * NCH);
    const ushort8 v2 = *(const ushort8*)(fcol + (long)i2 * NCH);
    const ushort8 v3 = *(const ushort8*)(fcol + (long)i3 * NCH);
#pragma unroll
    for (int k = 0; k < 8; ++k) {
      acc[k] += b2f(v0[k]); acc[k] += b2f(v1[k]);
      acc[k] += b2f(v2[k]); acc[k] += b2f(v3[k]);
    }
    j += 4;
  }
  for (; j < m; ++j) {
    const ushort8 v = *(const ushort8*)(fcol + (long)sl[j] * NCH);
#pragma unroll
    for (int k = 0; k < 8; ++k) acc[k] += b2f(v[k]);
  }

  // overflow pass (normally empty; keeps exactness for any input)
  const int on = *ovf_n;
  for (int o = 0; o < on; ++o) {
    const int2 p = ovf[o];
    if (p.x == g) {
      const ushort8 v = *(const ushort8*)(fcol + (long)p.y * NCH);
#pragma unroll
      for (int k = 0; k < 8; ++k) acc[k] += b2f(v[k]);
    }
  }

  int dd = (deg < 1) ? 1 : deg;
  const float inv = 1.f / (float)dd;
  ushort8 r;
#pragma unroll
  for (int k = 0; k < 8; ++k) r[k] = f2b(acc[k] * inv);
  *(ushort8*)(agg + (long)g * NCH + col) = r;
}

// ---------------- MFMA dual-GEMM ----------------
// out[m][n] = relu?( sum_k agg[m][k]Wl[n][k] + self[m][k]Wr[n][k] + bias[n] )
// LDS-free: wave = 32 rows x 128 cols; K'=256 in 8 chunks; A-frags from
// global bf16 (16B/lane), B-frags from prepacked weights (L2-hot, 64KB).
__global__ __launch_bounds__(256) void k_gemm(
    const unsigned short* __restrict__ Ag,   // agg  bf16 [M][128]
    const unsigned short* __restrict__ Sf,   // self bf16 [M][128]
    const unsigned short* __restrict__ pack, // [8][8][64][8] bf16
    const float* __restrict__ bsum,          // [128]
    unsigned short* __restrict__ outb,       // bf16 out (layer1) or null
    float* __restrict__ outf,                // f32 out (layer2) or null
    int M, int NO, int do_relu) {
  const int wave = threadIdx.x >> 6;
  const int lane = threadIdx.x & 63;
  const int R = blockIdx.x * 128 + wave * 32;  // 2 m-tiles: R, R+16
  const int mrow = lane & 15;
  const int koct = (lane >> 4) * 8;

  int r0 = R + mrow;       if (r0 > M - 1) r0 = M - 1;
  int r1 = R + 16 + mrow;  if (r1 > M - 1) r1 = M - 1;

  f32x4 acc[2][8];
#pragma unroll
  for (int mt = 0; mt < 2; ++mt)
#pragma unroll
    for (int t = 0; t < 8; ++t) acc[mt][t] = (f32x4){0.f, 0.f, 0.f, 0.f};

#pragma unroll
  for (int c = 0; c < 8; ++c) {
    const unsigned short* __restrict__ Abase = (c < 4) ? Ag : Sf;
    const int k0 = (c & 3) * 32;
    const bf16x8 a0 = *(const bf16x8*)(Abase + (long)r0 * NCH + k0 + koct);
    const bf16x8 a1 = *(const bf16x8*)(Abase + (long)r1 * NCH + k0 + koct);
    const unsigned short* bp = pack + ((long)(c * 8) * 64 + lane) * 8;
#pragma unroll
    for (int t = 0; t < 8; ++t) {
      const bf16x8 bfrag = *(const bf16x8*)(bp + (long)t * 512);
      acc[0][t] = __builtin_amdgcn_mfma_f32_16x16x32_bf16(a0, bfrag, acc[0][t], 0, 0, 0);
      acc[1][t] = __builtin_amdgcn_mfma_f32_16x16x32_bf16(a1, bfrag, acc[1][t], 0, 0, 0);
    }
  }

  // epilogue: C/D layout col=lane&15, row=(lane>>4)*4+reg
  const int nloc = lane & 15;
  const int rquad = (lane >> 4) * 4;
#pragma unroll
  for (int mt = 0; mt < 2; ++mt) {
#pragma unroll
    for (int t = 0; t < 8; ++t) {
      const int n = t * 16 + nloc;
      const float bias = bsum[n];
#pragma unroll
      for (int r = 0; r < 4; ++r) {
        const int m = R + mt * 16 + rquad + r;
        if (m < M && n < NO) {
          float v = acc[mt][t][r] + bias;
          if (do_relu) v = fmaxf(v, 0.f);
          if (outb) outb[(long)m * NCH + n] = f2b(v);
          else outf[(long)m * NO + n] = v;
        }
      }
    }
  }
}

// ---------------- launch ----------------

extern "C" void kernel_launch(void* const* d_in, const int* in_sizes, int n_in,
                              void* d_out, int out_size, void* d_ws, size_t ws_size,
                              hipStream_t stream) {
  const float* x = (const float*)d_in[0];
  const int* ei = (const int*)d_in[1];
  const float* W1l = (const float*)d_in[2];
  const float* b1l = (const float*)d_in[3];
  const float* W1r = (const float*)d_in[4];
  const float* b1r = (const float*)d_in[5];
  const float* W2l = (const float*)d_in[6];
  const float* b2l = (const float*)d_in[7];
  const float* W2r = (const float*)d_in[8];
  const float* b2r = (const float*)d_in[9];
  float* out = (float*)d_out;

  const int N = in_sizes[0] / NCH;  // 40000
  const int E = in_sizes[1] / 2;    // 640000
  const int NOUT = out_size / N;    // 121

  const int* src = ei;
  const int* dst = ei + E;

  char* w = (char*)d_ws;
  auto alloc = [&](size_t bytes) {
    char* p = w;
    w += (bytes + 255) & ~(size_t)255;
    return p;
  };
  unsigned short* xb = (unsigned short*)alloc((size_t)N * NCH * 2);
  unsigned short* hb = (unsigned short*)alloc((size_t)N * NCH * 2);
  unsigned short* aggb = (unsigned short*)alloc((size_t)N * NCH * 2);
  unsigned short* pack1 = (unsigned short*)alloc(8 * 8 * 64 * 8 * 2);
  unsigned short* pack2 = (unsigned short*)alloc(8 * 8 * 64 * 8 * 2);
  float* bsum1 = (float*)alloc(128 * 4);
  float* bsum2 = (float*)alloc(128 * 4);
  int* cnt = (int*)alloc((size_t)(N + 1) * 4);  // [cnt(N) | ovf_n(1)]
  int* ovf_n = cnt + N;
  int* slot = (int*)alloc((size_t)N * CAP * 4);
  int2* ovf = (int2*)alloc((size_t)E * 8);

  const int n4 = N * NCH / 4;
  const int nbBkt = (E + 256 * EPT - 1) / (256 * EPT);  // 313
  const int nbCvt = (n4 + 255) / 256;                   // 5000

  // zero degree counters + overflow count
  hipMemsetAsync(cnt, 0, (size_t)(N + 1) * 4, stream);

  // bucket || convert || prepack in one dispatch
  k_main<<<nbBkt + nbCvt + 32, 256, 0, stream>>>(
      src, dst, E, cnt, slot, ovf_n, ovf,
      x, xb, n4,
      W1l, W1r, b1l, b1r, W2l, W2r, b2l, b2r,
      pack1, pack2, bsum1, bsum2, NOUT, nbBkt, nbCvt);

  const int gaggr = (N * 16 + 255) / 256;  // 2500
  const int gblk = (N + 127) / 128;        // 313

  // layer 1 (relu, bf16 out)
  k_agg<<<gaggr, 256, 0, stream>>>(xb, cnt, slot, ovf_n, ovf, aggb, N);
  k_gemm<<<gblk, 256, 0, stream>>>(aggb, xb, pack1, bsum1, hb, (float*)nullptr,
                                   N, NCH, 1);
  // layer 2 (f32 out)
  k_agg<<<gaggr, 256, 0, stream>>>(hb, cnt, slot, ovf_n, ovf, aggb, N);
  k_gemm<<<gblk, 256, 0, stream>>>(aggb, hb, pack2, bsum2, (unsigned short*)nullptr,
                                   out, N, NOUT, 0);
}

// Round 9
// 203.950 us; speedup vs baseline: 1.2005x; 1.0309x over previous
//
#include <hip/hip_runtime.h>

// GraphSAGE 2-layer inference. N=40000, E=640000, C=128, OUT=121.
// R9: CSR-build atomics moved OFF the device-scope path. R6/R7/R8 tripled
// evidence that 640K device-scope atomics are throughput-bound (~5.8/clk
// chip-wide) regardless of MLP/padding. Fix: per-XCD counters indexed by
// HW_REG_XCC_ID + WORKGROUP-scope atomicFetchAdd -> executes at the local
// XCD L2 (no cross-XCD coherence round-trip). Counter cntx[node][xcc] is
// only ever touched by blocks on XCD xcc => L2-local atomicity is enough.
// Slots: ushort slot[node][xcc*16+pos] (per-XCD cap 16; Poisson(2) => ovf
// ~never; device-scope overflow list keeps exactness). Cross-XCD
// byte-granular line merging proven safe by R6-R8 slot stores.
// 6 dispatches: memset -> k_main(bucket||convert||prepack) -> agg -> gemm -> agg -> gemm.

#define NCH 128
#define CAPX 16  // per-XCD slots per node
#define EPT 8    // edges per thread in bucket phase

typedef __bf16 bf16x8 __attribute__((ext_vector_type(8)));
typedef float f32x4 __attribute__((ext_vector_type(4)));
typedef unsigned short ushort8 __attribute__((ext_vector_type(8)));

static __device__ __forceinline__ unsigned short f2b(float f) {
  return __builtin_bit_cast(unsigned short, static_cast<__bf16>(f));
}
static __device__ __forceinline__ float b2f(unsigned short u) {
  union { unsigned int i; float f; } v;
  v.i = ((unsigned int)u) << 16;
  return v.f;
}

// ---------------- fused main: bucket CSR || x->bf16 || weight prepack ----------------
__global__ __launch_bounds__(256) void k_main(
    const int* __restrict__ src, const int* __restrict__ dst, int E,
    int* __restrict__ cntx, unsigned short* __restrict__ slotu,
    int* __restrict__ ovf_n, int2* __restrict__ ovf,
    const float* __restrict__ x, unsigned short* __restrict__ xb, int n4,
    const float* __restrict__ W1l, const float* __restrict__ W1r,
    const float* __restrict__ b1l, const float* __restrict__ b1r,
    const float* __restrict__ W2l, const float* __restrict__ W2r,
    const float* __restrict__ b2l, const float* __restrict__ b2r,
    unsigned short* __restrict__ pack1, unsigned short* __restrict__ pack2,
    float* __restrict__ bsum1, float* __restrict__ bsum2, int NOUT,
    int nbBkt, int nbCvt) {
  int blk = blockIdx.x;
  if (blk < nbBkt) {  // bucket: 8 edges/thread, L2-local atomics
    unsigned int xcc;
    asm volatile("s_getreg_b32 %0, hwreg(HW_REG_XCC_ID)" : "=s"(xcc));
    xcc &= 7u;
    const int base = blk * (256 * EPT) + (int)threadIdx.x;
    int d[EPT], s[EPT], pos[EPT];
#pragma unroll
    for (int j = 0; j < EPT; ++j) {
      const int e = base + j * 256;
      const bool ok = e < E;
      d[j] = ok ? dst[e] : -1;
      s[j] = ok ? src[e] : 0;
    }
#pragma unroll
    for (int j = 0; j < EPT; ++j) {
      pos[j] = (d[j] >= 0)
          ? __hip_atomic_fetch_add(&cntx[(long)d[j] * 8 + xcc], 1,
                                   __ATOMIC_RELAXED, __HIP_MEMORY_SCOPE_WORKGROUP)
          : 0;
    }
#pragma unroll
    for (int j = 0; j < EPT; ++j) {
      if (d[j] >= 0) {
        if (pos[j] < CAPX)
          slotu[(long)d[j] * 128 + xcc * CAPX + pos[j]] = (unsigned short)s[j];
        else {
          int o = atomicAdd(ovf_n, 1);  // device-scope, ~never taken
          ovf[o] = make_int2(d[j], s[j]);
        }
      }
    }
    return;
  }
  blk -= nbBkt;
  if (blk < nbCvt) {  // fp32 -> bf16 convert
    int i = blk * 256 + threadIdx.x;
    if (i < n4) {
      float4 v = ((const float4*)x)[i];
      ushort4 r;
      r.x = f2b(v.x); r.y = f2b(v.y); r.z = f2b(v.z); r.w = f2b(v.w);
      ((ushort4*)xb)[i] = r;
    }
    return;
  }
  blk -= nbCvt;  // prepack: 32 blocks, 16 per layer
  const int layer = blk >> 4;
  const float* Wl = layer ? W2l : W1l;
  const float* Wr = layer ? W2r : W1r;
  const float* bl = layer ? b2l : b1l;
  const float* br = layer ? b2r : b1r;
  unsigned short* pack = layer ? pack2 : pack1;
  float* bsum = layer ? bsum2 : bsum1;
  const int NO = layer ? NOUT : NCH;
  int tid = (blk & 15) * 256 + threadIdx.x;  // 0..4095
  int c = tid >> 9;
  int t = (tid >> 6) & 7;
  int l = tid & 63;
  int n = t * 16 + (l & 15);
  int kb = c * 32 + ((l >> 4) << 3);
  unsigned short o[8];
#pragma unroll
  for (int j = 0; j < 8; ++j) {
    int k = kb + j;
    float v = 0.f;
    if (n < NO) v = (k < 128) ? Wl[n * 128 + k] : Wr[n * 128 + (k - 128)];
    o[j] = f2b(v);
  }
  ushort4 lo, hi;
  lo.x = o[0]; lo.y = o[1]; lo.z = o[2]; lo.w = o[3];
  hi.x = o[4]; hi.y = o[5]; hi.z = o[6]; hi.w = o[7];
  *(ushort4*)(pack + (long)tid * 8) = lo;
  *(ushort4*)(pack + (long)tid * 8 + 4) = hi;
  if (tid < 128) bsum[tid] = (tid < NO) ? (bl[tid] + br[tid]) : 0.f;
}

// ---------------- mean aggregation ----------------
// Block = 16 groups x 16 lanes; group = one node. Phase A: read the node's
// 8 per-XCD counts (one 32B row), compact its <=128 ushort indices into LDS.
// Phase B: proven 8-deep ushort8 row gather (8 x 16B in flight per lane).
__global__ __launch_bounds__(256) void k_agg(
    const unsigned short* __restrict__ feat, const int* __restrict__ cntx,
    const unsigned short* __restrict__ slotu, const int* __restrict__ ovf_n,
    const int2* __restrict__ ovf, unsigned short* __restrict__ agg, int N) {
  __shared__ unsigned short list[16][128];
  __shared__ int degs[16], ms[16];
  const int lg = threadIdx.x >> 4;  // group in block
  const int ln = threadIdx.x & 15;  // lane in group
  const int g = blockIdx.x * 16 + lg;

  // ---- phase A: build compact index list ----
  if (g < N) {
    const int4 cA = *(const int4*)(cntx + (long)g * 8);
    const int4 cB = *(const int4*)(cntx + (long)g * 8 + 4);
    const int c[8] = {cA.x, cA.y, cA.z, cA.w, cB.x, cB.y, cB.z, cB.w};
    int deg = 0, p = 0, myoff = 0, mycc = 0;
#pragma unroll
    for (int xx = 0; xx < 8; ++xx) {
      const int cc = (c[xx] < CAPX) ? c[xx] : CAPX;
      if (ln == xx) { myoff = p; mycc = cc; }
      p += cc;
      deg += c[xx];
    }
    if (ln == 0) { degs[lg] = deg; ms[lg] = p; }
    if (ln < 8 && mycc > 0) {
      const unsigned short* sp = slotu + (long)g * 128 + ln * CAPX;
      for (int i = 0; i < mycc; ++i) list[lg][myoff + i] = sp[i];
    }
  } else if (ln == 0) {
    degs[lg] = 0; ms[lg] = 0;
  }
  __syncthreads();

  if (g >= N) return;
  const int m = ms[lg];
  const int col = ln * 8;
  const unsigned short* fcol = feat + col;

  float acc[8];
#pragma unroll
  for (int k = 0; k < 8; ++k) acc[k] = 0.f;

  const unsigned short* __restrict__ il = list[lg];
  int j = 0;
  for (; j + 7 < m; j += 8) {
    const int i0 = il[j + 0], i1 = il[j + 1], i2 = il[j + 2], i3 = il[j + 3];
    const int i4 = il[j + 4], i5 = il[j + 5], i6 = il[j + 6], i7 = il[j + 7];
    const ushort8 v0 = *(const ushort8*)(fcol + (long)i0 * NCH);
    const ushort8 v1 = *(const ushort8*)(fcol + (long)i1 * NCH);
    const ushort8 v2 = *(const ushort8*)(fcol + (long)i2 * NCH);
    const ushort8 v3 = *(const ushort8*)(fcol + (long)i3 * NCH);
    const ushort8 v4 = *(const ushort8*)(fcol + (long)i4 * NCH);
    const ushort8 v5 = *(const ushort8*)(fcol + (long)i5 * NCH);
    const ushort8 v6 = *(const ushort8*)(fcol + (long)i6 * NCH);
    const ushort8 v7 = *(const ushort8*)(fcol + (long)i7 * NCH);
#pragma unroll
    for (int k = 0; k < 8; ++k) {
      acc[k] += b2f(v0[k]); acc[k] += b2f(v1[k]);
      acc[k] += b2f(v2[k]); acc[k] += b2f(v3[k]);
      acc[k] += b2f(v4[k]); acc[k] += b2f(v5[k]);
      acc[k] += b2f(v6[k]); acc[k] += b2f(v7[k]);
    }
  }
  if (j + 3 < m) {
    const int i0 = il[j + 0], i1 = il[j + 1], i2 = il[j + 2], i3 = il[j + 3];
    const ushort8 v0 = *(const ushort8*)(fcol + (long)i0 * NCH);
    const ushort8 v1 = *(const ushort8*)(fcol + (long)i1 * NCH);
    const ushort8 v2 = *(const ushort8*)(fcol + (long)i2 * NCH);
    const ushort8 v3 = *(const ushort8*)(fcol + (long)i3 * NCH);
#pragma unroll
    for (int k = 0; k < 8; ++k) {
      acc[k] += b2f(v0[k]); acc[k] += b2f(v1[k]);
      acc[k] += b2f(v2[k]); acc[k] += b2f(v3[k]);
    }
    j += 4;
  }
  for (; j < m; ++j) {
    const ushort8 v = *(const ushort8*)(fcol + (long)il[j] * NCH);
#pragma unroll
    for (int k = 0; k < 8; ++k) acc[k] += b2f(v[k]);
  }

  // overflow pass (normally empty; keeps exactness for any input)
  const int on = *ovf_n;
  for (int o = 0; o < on; ++o) {
    const int2 p = ovf[o];
    if (p.x == g) {
      const ushort8 v = *(const ushort8*)(fcol + (long)p.y * NCH);
#pragma unroll
      for (int k = 0; k < 8; ++k) acc[k] += b2f(v[k]);
    }
  }

  const int deg = degs[lg];
  const int dd = (deg < 1) ? 1 : deg;
  const float inv = 1.f / (float)dd;
  ushort8 r;
#pragma unroll
  for (int k = 0; k < 8; ++k) r[k] = f2b(acc[k] * inv);
  *(ushort8*)(agg + (long)g * NCH + col) = r;
}

// ---------------- MFMA dual-GEMM ----------------
// out[m][n] = relu?( sum_k agg[m][k]Wl[n][k] + self[m][k]Wr[n][k] + bias[n] )
__global__ __launch_bounds__(256) void k_gemm(
    const unsigned short* __restrict__ Ag,   // agg  bf16 [M][128]
    const unsigned short* __restrict__ Sf,   // self bf16 [M][128]
    const unsigned short* __restrict__ pack, // [8][8][64][8] bf16
    const float* __restrict__ bsum,          // [128]
    unsigned short* __restrict__ outb,       // bf16 out (layer1) or null
    float* __restrict__ outf,                // f32 out (layer2) or null
    int M, int NO, int do_relu) {
  const int wave = threadIdx.x >> 6;
  const int lane = threadIdx.x & 63;
  const int R = blockIdx.x * 128 + wave * 32;  // 2 m-tiles: R, R+16
  const int mrow = lane & 15;
  const int koct = (lane >> 4) * 8;

  int r0 = R + mrow;       if (r0 > M - 1) r0 = M - 1;
  int r1 = R + 16 + mrow;  if (r1 > M - 1) r1 = M - 1;

  f32x4 acc[2][8];
#pragma unroll
  for (int mt = 0; mt < 2; ++mt)
#pragma unroll
    for (int t = 0; t < 8; ++t) acc[mt][t] = (f32x4){0.f, 0.f, 0.f, 0.f};

#pragma unroll
  for (int c = 0; c < 8; ++c) {
    const unsigned short* __restrict__ Abase = (c < 4) ? Ag : Sf;
    const int k0 = (c & 3) * 32;
    const bf16x8 a0 = *(const bf16x8*)(Abase + (long)r0 * NCH + k0 + koct);
    const bf16x8 a1 = *(const bf16x8*)(Abase + (long)r1 * NCH + k0 + koct);
    const unsigned short* bp = pack + ((long)(c * 8) * 64 + lane) * 8;
#pragma unroll
    for (int t = 0; t < 8; ++t) {
      const bf16x8 bfrag = *(const bf16x8*)(bp + (long)t * 512);
      acc[0][t] = __builtin_amdgcn_mfma_f32_16x16x32_bf16(a0, bfrag, acc[0][t], 0, 0, 0);
      acc[1][t] = __builtin_amdgcn_mfma_f32_16x16x32_bf16(a1, bfrag, acc[1][t], 0, 0, 0);
    }
  }

  // epilogue: C/D layout col=lane&15, row=(lane>>4)*4+reg
  const int nloc = lane & 15;
  const int rquad = (lane >> 4) * 4;
#pragma unroll
  for (int mt = 0; mt < 2; ++mt) {
#pragma unroll
    for (int t = 0; t < 8; ++t) {
      const int n = t * 16 + nloc;
      const float bias = bsum[n];
#pragma unroll
      for (int r = 0; r < 4; ++r) {
        const int m = R + mt * 16 + rquad + r;
        if (m < M && n < NO) {
          float v = acc[mt][t][r] + bias;
          if (do_relu) v = fmaxf(v, 0.f);
          if (outb) outb[(long)m * NCH + n] = f2b(v);
          else outf[(long)m * NO + n] = v;
        }
      }
    }
  }
}

// ---------------- launch ----------------

extern "C" void kernel_launch(void* const* d_in, const int* in_sizes, int n_in,
                              void* d_out, int out_size, void* d_ws, size_t ws_size,
                              hipStream_t stream) {
  const float* x = (const float*)d_in[0];
  const int* ei = (const int*)d_in[1];
  const float* W1l = (const float*)d_in[2];
  const float* b1l = (const float*)d_in[3];
  const float* W1r = (const float*)d_in[4];
  const float* b1r = (const float*)d_in[5];
  const float* W2l = (const float*)d_in[6];
  const float* b2l = (const float*)d_in[7];
  const float* W2r = (const float*)d_in[8];
  const float* b2r = (const float*)d_in[9];
  float* out = (float*)d_out;

  const int N = in_sizes[0] / NCH;  // 40000
  const int E = in_sizes[1] / 2;    // 640000
  const int NOUT = out_size / N;    // 121

  const int* src = ei;
  const int* dst = ei + E;

  char* w = (char*)d_ws;
  auto alloc = [&](size_t bytes) {
    char* p = w;
    w += (bytes + 255) & ~(size_t)255;
    return p;
  };
  unsigned short* xb = (unsigned short*)alloc((size_t)N * NCH * 2);
  unsigned short* hb = (unsigned short*)alloc((size_t)N * NCH * 2);
  unsigned short* aggb = (unsigned short*)alloc((size_t)N * NCH * 2);
  unsigned short* pack1 = (unsigned short*)alloc(8 * 8 * 64 * 8 * 2);
  unsigned short* pack2 = (unsigned short*)alloc(8 * 8 * 64 * 8 * 2);
  float* bsum1 = (float*)alloc(128 * 4);
  float* bsum2 = (float*)alloc(128 * 4);
  int* cntx = (int*)alloc(((size_t)N * 8 + 1) * 4);  // [node][xcc] + ovf_n
  int* ovf_n = cntx + (size_t)N * 8;
  unsigned short* slotu = (unsigned short*)alloc((size_t)N * 128 * 2);
  int2* ovf = (int2*)alloc((size_t)E * 8);

  const int n4 = N * NCH / 4;
  const int nbBkt = (E + 256 * EPT - 1) / (256 * EPT);  // 313
  const int nbCvt = (n4 + 255) / 256;                   // 5000

  // zero per-XCD degree counters + overflow count
  hipMemsetAsync(cntx, 0, ((size_t)N * 8 + 1) * 4, stream);

  // bucket || convert || prepack in one dispatch
  k_main<<<nbBkt + nbCvt + 32, 256, 0, stream>>>(
      src, dst, E, cntx, slotu, ovf_n, ovf,
      x, xb, n4,
      W1l, W1r, b1l, b1r, W2l, W2r, b2l, b2r,
      pack1, pack2, bsum1, bsum2, NOUT, nbBkt, nbCvt);

  const int gaggr = (N + 15) / 16;   // 2500 (16 nodes per 256-thread block)
  const int gblk = (N + 127) / 128;  // 313

  // layer 1 (relu, bf16 out)
  k_agg<<<gaggr, 256, 0, stream>>>(xb, cntx, slotu, ovf_n, ovf, aggb, N);
  k_gemm<<<gblk, 256, 0, stream>>>(aggb, xb, pack1, bsum1, hb, (float*)nullptr,
                                   N, NCH, 1);
  // layer 2 (f32 out)
  k_agg<<<gaggr, 256, 0, stream>>>(hb, cntx, slotu, ovf_n, ovf, aggb, N);
  k_gemm<<<gblk, 256, 0, stream>>>(aggb, hb, pack2, bsum2, (unsigned short*)nullptr,
                                   out, N, NOUT, 0);
}